// Round 5
// baseline (49.776 us; speedup 1.0000x reference)
//
#include <hip/hip_runtime.h>
#include <math.h>

#define B 16
#define N 4096
#define K 4096
#define OBJ_ELEMS (8*512*3)     // 12288 per batch
#define OBJ_VEC4  (OBJ_ELEMS/4) // 3072 float4 per batch
#define KSEG 16
#define KS (K/KSEG)             // 256 ori points per segment
#define NSPLIT 4
#define NCHUNK (N/NSPLIT)       // 1024 adv points per block
#define BLK1 256
#define P (NCHUNK/BLK1)         // 4 adv points per thread
#define M 16                    // n-splits in the reduce
#define NR (N/M)                // 256 points per reduce block
#define OBJ_V4_PER_BLK (OBJ_VEC4/M) // 192 float4 per reduce block
#define CD_W 0.2f
#define EPS_F 1e-7f

// ws layout (floats):
//   [0,        KSEG*B*N)  partial minima of (o2 - 2*dot)
//   [RES_OFF,  +2*B)      per-batch chamfer sum [B], l2 sq-sum [B]
//   [CNT_OFF]             completion counter (int)
#define PART_SZ (KSEG*B*N)
#define RES_OFF PART_SZ
#define CNT_OFF (RES_OFF + 2*B)

__global__ __launch_bounds__(BLK1) void chamfer_part_kernel(
    const float* __restrict__ adv, const float* __restrict__ ori,
    float* __restrict__ part, float* __restrict__ res, int* __restrict__ cnt)
{
    __shared__ float4 lo[KS];
    const int nseg = blockIdx.x;
    const int kseg = blockIdx.y;
    const int b    = blockIdx.z;
    const int tid  = threadIdx.x;

    // per-call state reset (ws is poisoned once, never re-poisoned)
    if (nseg == 0 && kseg == 0 && b == 0) {
        if (tid < 2*B) res[tid] = 0.f;
        if (tid == 2*B) *cnt = 0;
    }

    // stage + pack this block's ori segment into LDS {-2x,-2y,-2z,o2}
    {
        int kk = (b*K + kseg*KS + tid) * 3;
        float x = ori[kk], y = ori[kk+1], z = ori[kk+2];
        lo[tid] = make_float4(-2.f*x, -2.f*y, -2.f*z, x*x + y*y + z*z);
    }

    // load this thread's P adv points into registers
    float ax[P], ay[P], az[P], m[P];
    #pragma unroll
    for (int p = 0; p < P; ++p) {
        int n = nseg*NCHUNK + tid + p * BLK1;
        ax[p] = adv[(b*N + n)*3 + 0];
        ay[p] = adv[(b*N + n)*3 + 1];
        az[p] = adv[(b*N + n)*3 + 2];
        m[p]  = INFINITY;
    }
    __syncthreads();

    #pragma unroll 4
    for (int k = 0; k < KS; k += 2) {
        float4 o0 = lo[k];
        float4 o1 = lo[k+1];
        #pragma unroll
        for (int p = 0; p < P; ++p) {
            float t0 = __builtin_fmaf(ax[p], o0.x, o0.w);
            t0 = __builtin_fmaf(ay[p], o0.y, t0);
            t0 = __builtin_fmaf(az[p], o0.z, t0);
            float t1 = __builtin_fmaf(ax[p], o1.x, o1.w);
            t1 = __builtin_fmaf(ay[p], o1.y, t1);
            t1 = __builtin_fmaf(az[p], o1.z, t1);
            m[p] = fminf(fminf(t0, t1), m[p]);   // -> v_min3_f32
        }
    }

    #pragma unroll
    for (int p = 0; p < P; ++p) {
        int n = nseg*NCHUNK + tid + p * BLK1;
        part[(kseg*B + b)*N + n] = m[p];
    }
}

__global__ __launch_bounds__(256) void reduce_final_kernel(
    const float* __restrict__ adv, const float* __restrict__ part,
    const float* __restrict__ adv_obj, const float* __restrict__ ori_obj,
    const float* __restrict__ w, float* __restrict__ res, int* __restrict__ cnt,
    float* __restrict__ out)
{
    const int mblk = blockIdx.x;
    const int b    = blockIdx.y;
    const int tid  = threadIdx.x;

    // chamfer: one n per thread; a2[n] + min over KSEG segments
    const int n = mblk * NR + tid;
    float x = adv[(b*N + n)*3 + 0];
    float y = adv[(b*N + n)*3 + 1];
    float z = adv[(b*N + n)*3 + 2];
    float a2 = x*x + y*y + z*z;
    float mn = INFINITY;
    #pragma unroll
    for (int s = 0; s < KSEG; s += 2) {
        float p0 = part[(s*B + b)*N + n];
        float p1 = part[((s+1)*B + b)*N + n];
        mn = fminf(fminf(p0, p1), mn);   // -> v_min3_f32
    }
    float csum = a2 + mn;

    // l2: vectorized squared-diff over this block's obj slice
    float lsum = 0.f;
    if (tid < OBJ_V4_PER_BLK) {
        int v4 = b*OBJ_VEC4 + mblk*OBJ_V4_PER_BLK + tid;
        float4 a = reinterpret_cast<const float4*>(adv_obj)[v4];
        float4 o = reinterpret_cast<const float4*>(ori_obj)[v4];
        float dx = a.x - o.x, dy = a.y - o.y, dz = a.z - o.z, dw = a.w - o.w;
        lsum = dx*dx + dy*dy + dz*dz + dw*dw;
    }

    // block reduce (4 waves of 64)
    #pragma unroll
    for (int off = 32; off; off >>= 1) {
        csum += __shfl_down(csum, off);
        lsum += __shfl_down(lsum, off);
    }
    __shared__ float scs[4], sls[4];
    int wave = tid >> 6, lane = tid & 63;
    if (lane == 0) { scs[wave] = csum; sls[wave] = lsum; }
    __syncthreads();
    if (tid == 0) {
        atomicAdd(&res[b],     scs[0] + scs[1] + scs[2] + scs[3]);
        atomicAdd(&res[B + b], sls[0] + sls[1] + sls[2] + sls[3]);
    }

    // last-block final combine
    __shared__ int lastflag;
    __threadfence();
    if (tid == 0) {
        int old = atomicAdd(cnt, 1);
        lastflag = (old == M*B - 1);
    }
    __syncthreads();
    if (lastflag) {
        __threadfence();   // acquire: make all res atomics visible
        if (tid < 64) {
            float cc = 0.f, ll = 0.f;
            if (tid < B) {
                float wt = w[tid];
                cc = (res[tid] / (float)N) * wt;
                ll = sqrtf(res[B + tid] + EPS_F) * wt;
            }
            #pragma unroll
            for (int off = 8; off; off >>= 1) {
                cc += __shfl_down(cc, off);
                ll += __shfl_down(ll, off);
            }
            if (tid == 0) out[0] = ll / (float)B + CD_W * (cc / (float)B);
        }
    }
}

extern "C" void kernel_launch(void* const* d_in, const int* in_sizes, int n_in,
                              void* d_out, int out_size, void* d_ws, size_t ws_size,
                              hipStream_t stream)
{
    const float* adv_pc  = (const float*)d_in[0];
    const float* ori_pc  = (const float*)d_in[1];
    const float* adv_obj = (const float*)d_in[2];
    const float* ori_obj = (const float*)d_in[3];
    const float* weights = (const float*)d_in[4];
    float* out = (float*)d_out;
    float* ws  = (float*)d_ws;

    float* part = ws;
    float* res  = ws + RES_OFF;
    int*   cnt  = (int*)(ws + CNT_OFF);

    // 1) chamfer partial minima (fused ori pack + state reset):
    //    grid = (NSPLIT, KSEG, B) = 1024 blocks of 256
    chamfer_part_kernel<<<dim3(NSPLIT, KSEG, B), dim3(BLK1), 0, stream>>>(
        adv_pc, ori_pc, part, res, cnt);

    // 2) reduction + weighted final combine (last-block pattern):
    //    grid = (M, B) = 256 blocks
    reduce_final_kernel<<<dim3(M, B), dim3(256), 0, stream>>>(
        adv_pc, part, adv_obj, ori_obj, weights, res, cnt, out);
}

// Round 6
// 46.916 us; speedup vs baseline: 1.0610x; 1.0610x over previous
//
#include <hip/hip_runtime.h>
#include <math.h>

#define B 16
#define N 4096
#define K 4096
#define OBJ_ELEMS (8*512*3)     // 12288 per batch
#define OBJ_VEC4  (OBJ_ELEMS/4) // 3072 float4 per batch
#define KSEG 16
#define KS (K/KSEG)             // 256 ori points per segment
#define NSPLIT 4
#define NCHUNK (N/NSPLIT)       // 1024 adv points per block
#define BLK1 256
#define P (NCHUNK/BLK1)         // 4 adv points per thread
#define M 16                    // n-splits in the reduce
#define NR (N/M)                // 256 points per reduce block
#define OBJ_V4_PER_BLK (OBJ_VEC4/M) // 192 float4 per reduce block
#define CD_W 0.2f
#define EPS_F 1e-7f

// ws layout (floats):
//   [0,            B*K*4)       packed ori {-2x,-2y,-2z,o2}
//   [PART_OFF,     +KSEG*B*N)   partial minima of (o2 - 2*dot)
//   [PC_OFF,       +B*M)        partial chamfer sums
//   [PL_OFF,       +B*M)        partial l2 sq-sums
#define PACKED_SZ (B*K*4)
#define PART_OFF  PACKED_SZ
#define PART_SZ   (KSEG*B*N)
#define PC_OFF    (PART_OFF + PART_SZ)
#define PL_OFF    (PC_OFF + B*M)

__global__ __launch_bounds__(256) void pack_ori_kernel(
    const float* __restrict__ ori, float* __restrict__ packed)
{
    int i = blockIdx.x * 256 + threadIdx.x;   // point index in [0, B*K)
    if (i >= B * K) return;
    float x = ori[i*3 + 0];
    float y = ori[i*3 + 1];
    float z = ori[i*3 + 2];
    float4 v = make_float4(-2.f*x, -2.f*y, -2.f*z, x*x + y*y + z*z);
    reinterpret_cast<float4*>(packed)[i] = v;
}

__global__ __launch_bounds__(BLK1) void chamfer_part_kernel(
    const float* __restrict__ adv, const float* __restrict__ packed,
    float* __restrict__ part)
{
    const int nseg = blockIdx.x;
    const int kseg = blockIdx.y;
    const int b    = blockIdx.z;
    const int tid  = threadIdx.x;

    // wave-uniform base into the packed ori segment -> scalar (SMEM) loads
    const float4* __restrict__ oseg =
        reinterpret_cast<const float4*>(packed) + (b*K + kseg*KS);

    // load this thread's P adv points into registers
    float ax[P], ay[P], az[P], m[P];
    #pragma unroll
    for (int p = 0; p < P; ++p) {
        int n = nseg*NCHUNK + tid + p * BLK1;
        ax[p] = adv[(b*N + n)*3 + 0];
        ay[p] = adv[(b*N + n)*3 + 1];
        az[p] = adv[(b*N + n)*3 + 2];
        m[p]  = INFINITY;
    }

    #pragma unroll 4
    for (int k = 0; k < KS; k += 2) {
        float4 o0 = oseg[k];       // uniform address -> s_load_dwordx4
        float4 o1 = oseg[k+1];
        #pragma unroll
        for (int p = 0; p < P; ++p) {
            float t0 = __builtin_fmaf(ax[p], o0.x, o0.w);
            t0 = __builtin_fmaf(ay[p], o0.y, t0);
            t0 = __builtin_fmaf(az[p], o0.z, t0);
            float t1 = __builtin_fmaf(ax[p], o1.x, o1.w);
            t1 = __builtin_fmaf(ay[p], o1.y, t1);
            t1 = __builtin_fmaf(az[p], o1.z, t1);
            m[p] = fminf(fminf(t0, t1), m[p]);   // -> v_min3_f32
        }
    }

    #pragma unroll
    for (int p = 0; p < P; ++p) {
        int n = nseg*NCHUNK + tid + p * BLK1;
        part[(kseg*B + b)*N + n] = m[p];
    }
}

__global__ __launch_bounds__(256) void reduce_partial_kernel(
    const float* __restrict__ adv, const float* __restrict__ part,
    const float* __restrict__ adv_obj, const float* __restrict__ ori_obj,
    float* __restrict__ partC, float* __restrict__ partL)
{
    const int mblk = blockIdx.x;
    const int b    = blockIdx.y;
    const int tid  = threadIdx.x;

    // chamfer: one n per thread; a2[n] + min over KSEG segments
    const int n = mblk * NR + tid;
    float x = adv[(b*N + n)*3 + 0];
    float y = adv[(b*N + n)*3 + 1];
    float z = adv[(b*N + n)*3 + 2];
    float a2 = x*x + y*y + z*z;
    float mn = INFINITY;
    #pragma unroll
    for (int s = 0; s < KSEG; s += 2) {
        float p0 = part[(s*B + b)*N + n];
        float p1 = part[((s+1)*B + b)*N + n];
        mn = fminf(fminf(p0, p1), mn);   // -> v_min3_f32
    }
    float csum = a2 + mn;

    // l2: vectorized squared-diff over this block's obj slice
    float lsum = 0.f;
    if (tid < OBJ_V4_PER_BLK) {
        int v4 = b*OBJ_VEC4 + mblk*OBJ_V4_PER_BLK + tid;
        float4 a = reinterpret_cast<const float4*>(adv_obj)[v4];
        float4 o = reinterpret_cast<const float4*>(ori_obj)[v4];
        float dx = a.x - o.x, dy = a.y - o.y, dz = a.z - o.z, dw = a.w - o.w;
        lsum = dx*dx + dy*dy + dz*dz + dw*dw;
    }

    // block reduce (4 waves of 64)
    #pragma unroll
    for (int off = 32; off; off >>= 1) {
        csum += __shfl_down(csum, off);
        lsum += __shfl_down(lsum, off);
    }
    __shared__ float scs[4], sls[4];
    int wave = tid >> 6, lane = tid & 63;
    if (lane == 0) { scs[wave] = csum; sls[wave] = lsum; }
    __syncthreads();
    if (tid == 0) {
        partC[b*M + mblk] = scs[0] + scs[1] + scs[2] + scs[3];
        partL[b*M + mblk] = sls[0] + sls[1] + sls[2] + sls[3];
    }
}

__global__ __launch_bounds__(256) void final_combine_kernel(
    const float* __restrict__ partC, const float* __restrict__ partL,
    const float* __restrict__ w, float* __restrict__ out)
{
    const int tid = threadIdx.x;          // 256 = B*M
    const int b   = tid >> 4;
    float c = partC[tid];
    float l = partL[tid];
    // reduce within 16-lane groups (one group per batch)
    #pragma unroll
    for (int off = 8; off; off >>= 1) {
        c += __shfl_down(c, off, 16);
        l += __shfl_down(l, off, 16);
    }
    __shared__ float sc[B], sl[B];
    if ((tid & 15) == 0) { sc[b] = c; sl[b] = l; }
    __syncthreads();
    if (tid < 64) {
        float cc = 0.f, ll = 0.f;
        if (tid < B) {
            float wt = w[tid];
            cc = (sc[tid] / (float)N) * wt;
            ll = sqrtf(sl[tid] + EPS_F) * wt;
        }
        #pragma unroll
        for (int off = 8; off; off >>= 1) {
            cc += __shfl_down(cc, off);
            ll += __shfl_down(ll, off);
        }
        if (tid == 0) out[0] = ll / (float)B + CD_W * (cc / (float)B);
    }
}

extern "C" void kernel_launch(void* const* d_in, const int* in_sizes, int n_in,
                              void* d_out, int out_size, void* d_ws, size_t ws_size,
                              hipStream_t stream)
{
    const float* adv_pc  = (const float*)d_in[0];
    const float* ori_pc  = (const float*)d_in[1];
    const float* adv_obj = (const float*)d_in[2];
    const float* ori_obj = (const float*)d_in[3];
    const float* weights = (const float*)d_in[4];
    float* out = (float*)d_out;
    float* ws  = (float*)d_ws;

    float* packed = ws;
    float* part   = ws + PART_OFF;
    float* partC  = ws + PC_OFF;
    float* partL  = ws + PL_OFF;

    // 1) pack ori points scaled by -2, with squared norms
    pack_ori_kernel<<<dim3((B*K + 255) / 256), dim3(256), 0, stream>>>(ori_pc, packed);

    // 2) chamfer partial minima (SGPR-broadcast ori, no LDS):
    //    grid = (NSPLIT, KSEG, B) = 1024 blocks of 256
    chamfer_part_kernel<<<dim3(NSPLIT, KSEG, B), dim3(BLK1), 0, stream>>>(adv_pc, packed, part);

    // 3) parallel per-batch reduction partials: grid = (M, B) = 256 blocks
    reduce_partial_kernel<<<dim3(M, B), dim3(256), 0, stream>>>(
        adv_pc, part, adv_obj, ori_obj, partC, partL);

    // 4) combine partials with weights into the scalar output
    final_combine_kernel<<<dim3(1), dim3(256), 0, stream>>>(partC, partL, weights, out);
}

// Round 7
// 38.001 us; speedup vs baseline: 1.3099x; 1.2346x over previous
//
#include <hip/hip_runtime.h>
#include <math.h>

#define B 16
#define N 4096
#define K 4096
#define OBJ_ELEMS (8*512*3)     // 12288 per batch
#define OBJ_VEC4  (OBJ_ELEMS/4) // 3072 float4 per batch
#define KSEG 16
#define KS (K/KSEG)             // 256 ori points per segment
#define NSPLIT 2
#define NCHUNK (N/NSPLIT)       // 2048 adv points per block
#define BLK1 256
#define P (NCHUNK/BLK1)         // 8 adv points per thread
#define M 16                    // n-splits in the reduce
#define NR (N/M)                // 256 points per reduce block
#define OBJ_V4_PER_BLK (OBJ_VEC4/M) // 192 float4 per reduce block
#define CD_W 0.2f
#define EPS_F 1e-7f

// ws layout (floats):
//   [0,            B*K*4)       packed ori {-2x,-2y,-2z,o2}
//   [PART_OFF,     +KSEG*B*N)   partial minima of (o2 - 2*dot)
//   [PC_OFF,       +B*M)        partial chamfer sums
//   [PL_OFF,       +B*M)        partial l2 sq-sums
#define PACKED_SZ (B*K*4)
#define PART_OFF  PACKED_SZ
#define PART_SZ   (KSEG*B*N)
#define PC_OFF    (PART_OFF + PART_SZ)
#define PL_OFF    (PC_OFF + B*M)

__global__ __launch_bounds__(256) void pack_ori_kernel(
    const float* __restrict__ ori, float* __restrict__ packed)
{
    int i = blockIdx.x * 256 + threadIdx.x;   // point index in [0, B*K)
    if (i >= B * K) return;
    float x = ori[i*3 + 0];
    float y = ori[i*3 + 1];
    float z = ori[i*3 + 2];
    float4 v = make_float4(-2.f*x, -2.f*y, -2.f*z, x*x + y*y + z*z);
    reinterpret_cast<float4*>(packed)[i] = v;
}

__global__ __launch_bounds__(BLK1) void chamfer_part_kernel(
    const float* __restrict__ adv, const float* __restrict__ packed,
    float* __restrict__ part)
{
    __shared__ float4 lo[KS];
    const int nseg = blockIdx.x;
    const int kseg = blockIdx.y;
    const int b    = blockIdx.z;
    const int tid  = threadIdx.x;

    // stage this block's ori segment into LDS (packed {-2x,-2y,-2z,o2});
    // KS == BLK1, so every thread stages exactly one float4
    lo[tid] = reinterpret_cast<const float4*>(packed)[b*K + kseg*KS + tid];

    // load this thread's P adv points into registers
    float ax[P], ay[P], az[P], m[P];
    #pragma unroll
    for (int p = 0; p < P; ++p) {
        int n = nseg*NCHUNK + tid + p * BLK1;
        ax[p] = adv[(b*N + n)*3 + 0];
        ay[p] = adv[(b*N + n)*3 + 1];
        az[p] = adv[(b*N + n)*3 + 2];
        m[p]  = INFINITY;
    }
    __syncthreads();

    #pragma unroll 4
    for (int k = 0; k < KS; k += 2) {
        float4 o0 = lo[k];
        float4 o1 = lo[k+1];
        #pragma unroll
        for (int p = 0; p < P; ++p) {
            float t0 = __builtin_fmaf(ax[p], o0.x, o0.w);
            t0 = __builtin_fmaf(ay[p], o0.y, t0);
            t0 = __builtin_fmaf(az[p], o0.z, t0);
            float t1 = __builtin_fmaf(ax[p], o1.x, o1.w);
            t1 = __builtin_fmaf(ay[p], o1.y, t1);
            t1 = __builtin_fmaf(az[p], o1.z, t1);
            m[p] = fminf(fminf(t0, t1), m[p]);   // -> v_min3_f32
        }
    }

    #pragma unroll
    for (int p = 0; p < P; ++p) {
        int n = nseg*NCHUNK + tid + p * BLK1;
        part[(kseg*B + b)*N + n] = m[p];
    }
}

__global__ __launch_bounds__(256) void reduce_partial_kernel(
    const float* __restrict__ adv, const float* __restrict__ part,
    const float* __restrict__ adv_obj, const float* __restrict__ ori_obj,
    float* __restrict__ partC, float* __restrict__ partL)
{
    const int mblk = blockIdx.x;
    const int b    = blockIdx.y;
    const int tid  = threadIdx.x;

    // chamfer: one n per thread; a2[n] + min over KSEG segments
    const int n = mblk * NR + tid;
    float x = adv[(b*N + n)*3 + 0];
    float y = adv[(b*N + n)*3 + 1];
    float z = adv[(b*N + n)*3 + 2];
    float a2 = x*x + y*y + z*z;
    float mn = INFINITY;
    #pragma unroll
    for (int s = 0; s < KSEG; s += 2) {
        float p0 = part[(s*B + b)*N + n];
        float p1 = part[((s+1)*B + b)*N + n];
        mn = fminf(fminf(p0, p1), mn);   // -> v_min3_f32
    }
    float csum = a2 + mn;

    // l2: vectorized squared-diff over this block's obj slice
    float lsum = 0.f;
    if (tid < OBJ_V4_PER_BLK) {
        int v4 = b*OBJ_VEC4 + mblk*OBJ_V4_PER_BLK + tid;
        float4 a = reinterpret_cast<const float4*>(adv_obj)[v4];
        float4 o = reinterpret_cast<const float4*>(ori_obj)[v4];
        float dx = a.x - o.x, dy = a.y - o.y, dz = a.z - o.z, dw = a.w - o.w;
        lsum = dx*dx + dy*dy + dz*dz + dw*dw;
    }

    // block reduce (4 waves of 64)
    #pragma unroll
    for (int off = 32; off; off >>= 1) {
        csum += __shfl_down(csum, off);
        lsum += __shfl_down(lsum, off);
    }
    __shared__ float scs[4], sls[4];
    int wave = tid >> 6, lane = tid & 63;
    if (lane == 0) { scs[wave] = csum; sls[wave] = lsum; }
    __syncthreads();
    if (tid == 0) {
        partC[b*M + mblk] = scs[0] + scs[1] + scs[2] + scs[3];
        partL[b*M + mblk] = sls[0] + sls[1] + sls[2] + sls[3];
    }
}

__global__ __launch_bounds__(256) void final_combine_kernel(
    const float* __restrict__ partC, const float* __restrict__ partL,
    const float* __restrict__ w, float* __restrict__ out)
{
    const int tid = threadIdx.x;          // 256 = B*M
    const int b   = tid >> 4;
    float c = partC[tid];
    float l = partL[tid];
    // reduce within 16-lane groups (one group per batch)
    #pragma unroll
    for (int off = 8; off; off >>= 1) {
        c += __shfl_down(c, off, 16);
        l += __shfl_down(l, off, 16);
    }
    __shared__ float sc[B], sl[B];
    if ((tid & 15) == 0) { sc[b] = c; sl[b] = l; }
    __syncthreads();
    if (tid < 64) {
        float cc = 0.f, ll = 0.f;
        if (tid < B) {
            float wt = w[tid];
            cc = (sc[tid] / (float)N) * wt;
            ll = sqrtf(sl[tid] + EPS_F) * wt;
        }
        #pragma unroll
        for (int off = 8; off; off >>= 1) {
            cc += __shfl_down(cc, off);
            ll += __shfl_down(ll, off);
        }
        if (tid == 0) out[0] = ll / (float)B + CD_W * (cc / (float)B);
    }
}

extern "C" void kernel_launch(void* const* d_in, const int* in_sizes, int n_in,
                              void* d_out, int out_size, void* d_ws, size_t ws_size,
                              hipStream_t stream)
{
    const float* adv_pc  = (const float*)d_in[0];
    const float* ori_pc  = (const float*)d_in[1];
    const float* adv_obj = (const float*)d_in[2];
    const float* ori_obj = (const float*)d_in[3];
    const float* weights = (const float*)d_in[4];
    float* out = (float*)d_out;
    float* ws  = (float*)d_ws;

    float* packed = ws;
    float* part   = ws + PART_OFF;
    float* partC  = ws + PC_OFF;
    float* partL  = ws + PL_OFF;

    // 1) pack ori points scaled by -2, with squared norms
    pack_ori_kernel<<<dim3((B*K + 255) / 256), dim3(256), 0, stream>>>(ori_pc, packed);

    // 2) chamfer partial minima: grid = (NSPLIT, KSEG, B) = 512 blocks of 256
    chamfer_part_kernel<<<dim3(NSPLIT, KSEG, B), dim3(BLK1), 0, stream>>>(adv_pc, packed, part);

    // 3) parallel per-batch reduction partials: grid = (M, B) = 256 blocks
    reduce_partial_kernel<<<dim3(M, B), dim3(256), 0, stream>>>(
        adv_pc, part, adv_obj, ori_obj, partC, partL);

    // 4) combine partials with weights into the scalar output
    final_combine_kernel<<<dim3(1), dim3(256), 0, stream>>>(partC, partL, weights, out);
}

// Round 8
// 36.919 us; speedup vs baseline: 1.3482x; 1.0293x over previous
//
#include <hip/hip_runtime.h>
#include <math.h>

typedef float f32x2 __attribute__((ext_vector_type(2)));

#define B 16
#define N 4096
#define K 4096
#define OBJ_ELEMS (8*512*3)     // 12288 per batch
#define OBJ_VEC4  (OBJ_ELEMS/4) // 3072 float4 per batch
#define KSEG 16
#define KS (K/KSEG)             // 256 ori points per segment
#define KP (KS/2)               // 128 ori pairs per segment
#define NSPLIT 4
#define NCHUNK (N/NSPLIT)       // 1024 adv points per block
#define BLK1 256
#define P (NCHUNK/BLK1)         // 4 adv points per thread
#define M 16                    // n-splits in the reduce
#define NR (N/M)                // 256 points per reduce block
#define OBJ_V4_PER_BLK (OBJ_VEC4/M) // 192 float4 per reduce block
#define CD_W 0.2f
#define EPS_F 1e-7f

// ws layout (floats):
//   [0,            B*K*4)       pair-SoA ori: per pair j: {-2x0,-2x1,-2y0,-2y1},{-2z0,-2z1,o2_0,o2_1}
//   [PART_OFF,     +KSEG*B*N)   partial minima of full sqdist (a2 folded in)
//   [PC_OFF,       +B*M)        partial chamfer sums
//   [PL_OFF,       +B*M)        partial l2 sq-sums
#define PACKED_SZ (B*K*4)
#define PART_OFF  PACKED_SZ
#define PART_SZ   (KSEG*B*N)
#define PC_OFF    (PART_OFF + PART_SZ)
#define PL_OFF    (PC_OFF + B*M)

__global__ __launch_bounds__(256) void pack_ori_kernel(
    const float* __restrict__ ori, float* __restrict__ packed)
{
    int j = blockIdx.x * 256 + threadIdx.x;   // pair index in [0, B*K/2)
    if (j >= B * K / 2) return;
    float x0 = ori[j*6 + 0], y0 = ori[j*6 + 1], z0 = ori[j*6 + 2];
    float x1 = ori[j*6 + 3], y1 = ori[j*6 + 4], z1 = ori[j*6 + 5];
    float w0 = x0*x0 + y0*y0 + z0*z0;
    float w1 = x1*x1 + y1*y1 + z1*z1;
    float4* p4 = reinterpret_cast<float4*>(packed);
    p4[j*2 + 0] = make_float4(-2.f*x0, -2.f*x1, -2.f*y0, -2.f*y1);
    p4[j*2 + 1] = make_float4(-2.f*z0, -2.f*z1, w0, w1);
}

__global__ __launch_bounds__(BLK1) void chamfer_part_kernel(
    const float* __restrict__ adv, const float* __restrict__ packed,
    float* __restrict__ part)
{
    __shared__ float4 lds4[KP*2];   // 4 KB: 128 pair entries x 32 B
    const int nseg = blockIdx.x;
    const int kseg = blockIdx.y;
    const int b    = blockIdx.z;
    const int tid  = threadIdx.x;

    // stage this block's ori pair-segment (4 KB, one float4 per thread)
    lds4[tid] = reinterpret_cast<const float4*>(packed)
                    [(b*(K/2) + kseg*KP)*2 + tid];

    // load this thread's P adv points; splat into f32x2 for packed math
    f32x2 axs[P], ays[P], azs[P];
    float a2[P], m[P];
    #pragma unroll
    for (int p = 0; p < P; ++p) {
        int n = nseg*NCHUNK + tid + p * BLK1;
        float ax = adv[(b*N + n)*3 + 0];
        float ay = adv[(b*N + n)*3 + 1];
        float az = adv[(b*N + n)*3 + 2];
        axs[p] = (f32x2){ax, ax};
        ays[p] = (f32x2){ay, ay};
        azs[p] = (f32x2){az, az};
        a2[p]  = ax*ax + ay*ay + az*az;
        m[p]   = INFINITY;
    }
    __syncthreads();

    const f32x2* __restrict__ lds2 = reinterpret_cast<const f32x2*>(lds4);
    #pragma unroll 2
    for (int j = 0; j < KP; ++j) {
        f32x2 xx = lds2[j*4 + 0];   // {-2x0, -2x1}
        f32x2 yy = lds2[j*4 + 1];   // {-2y0, -2y1}
        f32x2 zz = lds2[j*4 + 2];   // {-2z0, -2z1}
        f32x2 ww = lds2[j*4 + 3];   // {o2_0, o2_1}
        #pragma unroll
        for (int p = 0; p < P; ++p) {
            f32x2 t = __builtin_elementwise_fma(axs[p], xx, ww);   // v_pk_fma_f32
            t = __builtin_elementwise_fma(ays[p], yy, t);
            t = __builtin_elementwise_fma(azs[p], zz, t);
            m[p] = fminf(fminf(t.x, t.y), m[p]);                   // v_min3_f32
        }
    }

    #pragma unroll
    for (int p = 0; p < P; ++p) {
        int n = nseg*NCHUNK + tid + p * BLK1;
        part[(kseg*B + b)*N + n] = m[p] + a2[p];   // full sqdist
    }
}

__global__ __launch_bounds__(256) void reduce_partial_kernel(
    const float* __restrict__ part,
    const float* __restrict__ adv_obj, const float* __restrict__ ori_obj,
    float* __restrict__ partC, float* __restrict__ partL)
{
    const int mblk = blockIdx.x;
    const int b    = blockIdx.y;
    const int tid  = threadIdx.x;

    // chamfer: one n per thread; min over KSEG segments (a2 already folded)
    const int n = mblk * NR + tid;
    float mn = INFINITY;
    #pragma unroll
    for (int s = 0; s < KSEG; s += 2) {
        float p0 = part[(s*B + b)*N + n];
        float p1 = part[((s+1)*B + b)*N + n];
        mn = fminf(fminf(p0, p1), mn);   // -> v_min3_f32
    }
    float csum = mn;

    // l2: vectorized squared-diff over this block's obj slice
    float lsum = 0.f;
    if (tid < OBJ_V4_PER_BLK) {
        int v4 = b*OBJ_VEC4 + mblk*OBJ_V4_PER_BLK + tid;
        float4 a = reinterpret_cast<const float4*>(adv_obj)[v4];
        float4 o = reinterpret_cast<const float4*>(ori_obj)[v4];
        float dx = a.x - o.x, dy = a.y - o.y, dz = a.z - o.z, dw = a.w - o.w;
        lsum = dx*dx + dy*dy + dz*dz + dw*dw;
    }

    // block reduce (4 waves of 64)
    #pragma unroll
    for (int off = 32; off; off >>= 1) {
        csum += __shfl_down(csum, off);
        lsum += __shfl_down(lsum, off);
    }
    __shared__ float scs[4], sls[4];
    int wave = tid >> 6, lane = tid & 63;
    if (lane == 0) { scs[wave] = csum; sls[wave] = lsum; }
    __syncthreads();
    if (tid == 0) {
        partC[b*M + mblk] = scs[0] + scs[1] + scs[2] + scs[3];
        partL[b*M + mblk] = sls[0] + sls[1] + sls[2] + sls[3];
    }
}

__global__ __launch_bounds__(256) void final_combine_kernel(
    const float* __restrict__ partC, const float* __restrict__ partL,
    const float* __restrict__ w, float* __restrict__ out)
{
    const int tid = threadIdx.x;          // 256 = B*M
    const int b   = tid >> 4;
    float c = partC[tid];
    float l = partL[tid];
    // reduce within 16-lane groups (one group per batch)
    #pragma unroll
    for (int off = 8; off; off >>= 1) {
        c += __shfl_down(c, off, 16);
        l += __shfl_down(l, off, 16);
    }
    __shared__ float sc[B], sl[B];
    if ((tid & 15) == 0) { sc[b] = c; sl[b] = l; }
    __syncthreads();
    if (tid < 64) {
        float cc = 0.f, ll = 0.f;
        if (tid < B) {
            float wt = w[tid];
            cc = (sc[tid] / (float)N) * wt;
            ll = sqrtf(sl[tid] + EPS_F) * wt;
        }
        #pragma unroll
        for (int off = 8; off; off >>= 1) {
            cc += __shfl_down(cc, off);
            ll += __shfl_down(ll, off);
        }
        if (tid == 0) out[0] = ll / (float)B + CD_W * (cc / (float)B);
    }
}

extern "C" void kernel_launch(void* const* d_in, const int* in_sizes, int n_in,
                              void* d_out, int out_size, void* d_ws, size_t ws_size,
                              hipStream_t stream)
{
    const float* adv_pc  = (const float*)d_in[0];
    const float* ori_pc  = (const float*)d_in[1];
    const float* adv_obj = (const float*)d_in[2];
    const float* ori_obj = (const float*)d_in[3];
    const float* weights = (const float*)d_in[4];
    float* out = (float*)d_out;
    float* ws  = (float*)d_ws;

    float* packed = ws;
    float* part   = ws + PART_OFF;
    float* partC  = ws + PC_OFF;
    float* partL  = ws + PL_OFF;

    // 1) pack ori pairs into pair-SoA with -2 scaling + squared norms
    pack_ori_kernel<<<dim3((B*K/2 + 255) / 256), dim3(256), 0, stream>>>(ori_pc, packed);

    // 2) chamfer partial minima (packed-fp32 math): grid = (NSPLIT, KSEG, B)
    chamfer_part_kernel<<<dim3(NSPLIT, KSEG, B), dim3(BLK1), 0, stream>>>(adv_pc, packed, part);

    // 3) parallel per-batch reduction partials: grid = (M, B) = 256 blocks
    reduce_partial_kernel<<<dim3(M, B), dim3(256), 0, stream>>>(
        part, adv_obj, ori_obj, partC, partL);

    // 4) combine partials with weights into the scalar output
    final_combine_kernel<<<dim3(1), dim3(256), 0, stream>>>(partC, partL, weights, out);
}

// Round 9
// 30.296 us; speedup vs baseline: 1.6430x; 1.2186x over previous
//
#include <hip/hip_runtime.h>
#include <math.h>

typedef float f32x2 __attribute__((ext_vector_type(2)));

#define B 16
#define N 4096
#define K 4096
#define OBJ_ELEMS (8*512*3)     // 12288 per batch
#define OBJ_VEC4  (OBJ_ELEMS/4) // 3072 float4 per batch
#define NSEG 32
#define NCHUNK (N/NSEG)         // 128 adv points per block
#define BLK 256
#define KGROUPS 16              // K-groups per block (threads t>>4)
#define PLANES 16               // point-lanes per group (threads t&15)
#define P 8                     // points per thread (PLANES*P = NCHUNK)
#define KCHUNK 2048             // ori points staged per LDS pass
#define NKCH (K/KCHUNK)         // 2 passes
#define GPTS (KCHUNK/KGROUPS)   // 128 ori points per group per pass
#define GJ (GPTS/2)             // 64 pairs per group per pass
#define GSTRIDE (GPTS + 1)      // group stride in float4 (pad 1 -> bank skew)
#define OBJ_V4_PER_BLK (OBJ_VEC4/NSEG) // 96 float4 per block
#define CD_W 0.2f
#define EPS_F 1e-7f

// ws layout (floats): csum[B*NSEG] @0, lsq[B*NSEG] @512
#define CS_OFF 0
#define LS_OFF (B*NSEG)

__global__ __launch_bounds__(BLK) void chamfer_full_kernel(
    const float* __restrict__ adv, const float* __restrict__ ori,
    const float* __restrict__ adv_obj, const float* __restrict__ ori_obj,
    float* __restrict__ csum, float* __restrict__ lsq)
{
    __shared__ float4 olds[KGROUPS * GSTRIDE];  // 33 KB packed ori chunk
    __shared__ float  part_lds[KGROUPS * NCHUNK]; // 8 KB cross-group mins
    __shared__ float  red[4];

    const int nseg = blockIdx.x;
    const int b    = blockIdx.y;
    const int tid  = threadIdx.x;
    const int g    = tid >> 4;    // K-group
    const int i    = tid & 15;    // point lane

    // this thread's P adv points (splatted for packed math)
    f32x2 axs[P], ays[P], azs[P];
    float m[P];
    #pragma unroll
    for (int p = 0; p < P; ++p) {
        int n = nseg*NCHUNK + i + p*PLANES;
        float ax = adv[(b*N + n)*3 + 0];
        float ay = adv[(b*N + n)*3 + 1];
        float az = adv[(b*N + n)*3 + 2];
        axs[p] = (f32x2){ax, ax};
        ays[p] = (f32x2){ay, ay};
        azs[p] = (f32x2){az, az};
        m[p]   = INFINITY;
    }

    for (int c = 0; c < NKCH; ++c) {
        // stage+pack 2048 ori points: thread t packs 8 pts (4 pairs)
        // into its group's padded region
        {
            int pt0 = c*KCHUNK + tid*8;              // 8 consecutive points
            int sg  = tid >> 4;                      // == g
            int j0  = (tid & 15) * 4;                // first pair slot
            const float* src = ori + (b*K + pt0)*3;
            #pragma unroll
            for (int q = 0; q < 4; ++q) {            // pair q: points 2q,2q+1
                float x0 = src[q*6+0], y0 = src[q*6+1], z0 = src[q*6+2];
                float x1 = src[q*6+3], y1 = src[q*6+4], z1 = src[q*6+5];
                float w0 = x0*x0 + y0*y0 + z0*z0;
                float w1 = x1*x1 + y1*y1 + z1*z1;
                olds[sg*GSTRIDE + (j0+q)*2 + 0] =
                    make_float4(-2.f*x0, -2.f*x1, -2.f*y0, -2.f*y1);
                olds[sg*GSTRIDE + (j0+q)*2 + 1] =
                    make_float4(-2.f*z0, -2.f*z1, w0, w1);
            }
        }
        __syncthreads();

        // inner: this group's 64 pairs vs this thread's 8 points
        const float4* gb = &olds[g*GSTRIDE];
        #pragma unroll 4
        for (int j = 0; j < GJ; ++j) {
            float4 f0 = gb[j*2 + 0];   // {-2x0,-2x1,-2y0,-2y1}
            float4 f1 = gb[j*2 + 1];   // {-2z0,-2z1,o2_0,o2_1}
            f32x2 xx = (f32x2){f0.x, f0.y};
            f32x2 yy = (f32x2){f0.z, f0.w};
            f32x2 zz = (f32x2){f1.x, f1.y};
            f32x2 ww = (f32x2){f1.z, f1.w};
            #pragma unroll
            for (int p = 0; p < P; ++p) {
                f32x2 t = __builtin_elementwise_fma(axs[p], xx, ww);
                t = __builtin_elementwise_fma(ays[p], yy, t);
                t = __builtin_elementwise_fma(azs[p], zz, t);
                m[p] = fminf(fminf(t.x, t.y), m[p]);   // v_min3_f32
            }
        }
        __syncthreads();   // before restaging (and before part_lds phase)
    }

    // cross-group min: store per-group partial mins
    #pragma unroll
    for (int p = 0; p < P; ++p)
        part_lds[g*NCHUNK + i + p*PLANES] = m[p];
    __syncthreads();

    float val = 0.f;   // per-thread contribution to csum (waves 0,1)
    float lv  = 0.f;   // per-thread contribution to lsq  (waves 2,3)
    if (tid < NCHUNK) {
        // final min over the 16 groups + a2
        int pt = tid;
        float mn = INFINITY;
        #pragma unroll
        for (int gg = 0; gg < KGROUPS; gg += 2) {
            float p0 = part_lds[gg*NCHUNK + pt];
            float p1 = part_lds[(gg+1)*NCHUNK + pt];
            mn = fminf(fminf(p0, p1), mn);
        }
        int n = nseg*NCHUNK + pt;
        float ax = adv[(b*N + n)*3 + 0];
        float ay = adv[(b*N + n)*3 + 1];
        float az = adv[(b*N + n)*3 + 2];
        val = mn + (ax*ax + ay*ay + az*az);
    } else if (tid < NCHUNK + OBJ_V4_PER_BLK) {
        // obj L2 slice: 96 float4
        int idx = b*OBJ_VEC4 + nseg*OBJ_V4_PER_BLK + (tid - NCHUNK);
        float4 a = reinterpret_cast<const float4*>(adv_obj)[idx];
        float4 o = reinterpret_cast<const float4*>(ori_obj)[idx];
        float dx = a.x - o.x, dy = a.y - o.y, dz = a.z - o.z, dw = a.w - o.w;
        lv = dx*dx + dy*dy + dz*dz + dw*dw;
    }

    // per-wave shuffle sums (waves 0,1 carry val; waves 2,3 carry lv)
    float s = (tid < 2*64) ? val : lv;
    #pragma unroll
    for (int off = 32; off; off >>= 1) s += __shfl_down(s, off);
    if ((tid & 63) == 0) red[tid >> 6] = s;
    __syncthreads();
    if (tid == 0) {
        csum[b*NSEG + nseg] = red[0] + red[1];
        lsq [b*NSEG + nseg] = red[2] + red[3];
    }
}

__global__ __launch_bounds__(256) void final_kernel(
    const float* __restrict__ csum, const float* __restrict__ lsq,
    const float* __restrict__ w, float* __restrict__ out)
{
    const int tid = threadIdx.x;           // 256 threads, 512 partials each
    float c = csum[2*tid] + csum[2*tid + 1];
    float l = lsq [2*tid] + lsq [2*tid + 1];
    // 16 partial-pairs per batch live in one 16-lane group
    #pragma unroll
    for (int off = 8; off; off >>= 1) {
        c += __shfl_down(c, off, 16);
        l += __shfl_down(l, off, 16);
    }
    __shared__ float sc[B], sl[B];
    int bb = tid >> 4;
    if ((tid & 15) == 0) { sc[bb] = c; sl[bb] = l; }
    __syncthreads();
    if (tid < 64) {
        float cc = 0.f, ll = 0.f;
        if (tid < B) {
            float wt = w[tid];
            cc = (sc[tid] / (float)N) * wt;
            ll = sqrtf(sl[tid] + EPS_F) * wt;
        }
        #pragma unroll
        for (int off = 8; off; off >>= 1) {
            cc += __shfl_down(cc, off);
            ll += __shfl_down(ll, off);
        }
        if (tid == 0) out[0] = ll / (float)B + CD_W * (cc / (float)B);
    }
}

extern "C" void kernel_launch(void* const* d_in, const int* in_sizes, int n_in,
                              void* d_out, int out_size, void* d_ws, size_t ws_size,
                              hipStream_t stream)
{
    const float* adv_pc  = (const float*)d_in[0];
    const float* ori_pc  = (const float*)d_in[1];
    const float* adv_obj = (const float*)d_in[2];
    const float* ori_obj = (const float*)d_in[3];
    const float* weights = (const float*)d_in[4];
    float* out = (float*)d_out;
    float* ws  = (float*)d_ws;

    float* csum = ws + CS_OFF;
    float* lsq  = ws + LS_OFF;

    // 1) fused chamfer (full K in-block) + obj-L2 partials:
    //    grid = (NSEG, B) = 512 blocks of 256
    chamfer_full_kernel<<<dim3(NSEG, B), dim3(BLK), 0, stream>>>(
        adv_pc, ori_pc, adv_obj, ori_obj, csum, lsq);

    // 2) weighted final combine (1 block)
    final_kernel<<<dim3(1), dim3(256), 0, stream>>>(csum, lsq, weights, out);
}

// Round 10
// 22.765 us; speedup vs baseline: 2.1865x; 1.3308x over previous
//
#include <hip/hip_runtime.h>
#include <math.h>

typedef short bf16x8 __attribute__((ext_vector_type(8)));
typedef float f32x16 __attribute__((ext_vector_type(16)));

#define B 16
#define N 4096
#define K 4096
#define OBJ_ELEMS (8*512*3)        // 12288 per batch
#define OBJ_VEC4  (OBJ_ELEMS/4)    // 3072 float4 per batch
#define NSEG 32
#define NCHUNK (N/NSEG)            // 128 adv points per block (4 waves x 32)
#define BLK 256
#define WAVES 4
#define OBJ_V4_PER_BLK (OBJ_VEC4/NSEG) // 96 float4 per block
#define CD_W 0.2f
#define EPS_F 1e-7f

// ws layout (floats): csum[B*NSEG] @0, lsq[B*NSEG] @512
#define CS_OFF 0
#define LS_OFF (B*NSEG)

__device__ __forceinline__ unsigned short f2bf(float f) {
    unsigned int u = __float_as_uint(f);
    u = (u + 0x7FFFu + ((u >> 16) & 1u)) >> 16;   // RNE
    return (unsigned short)u;
}

__global__ __launch_bounds__(BLK) void chamfer_mfma_kernel(
    const float* __restrict__ adv, const float* __restrict__ ori,
    const float* __restrict__ adv_obj, const float* __restrict__ ori_obj,
    float* __restrict__ csum, float* __restrict__ lsq)
{
    __shared__ ushort4 slds[K];          // 32 KB: ori as bf16 {-2x,-2y,-2z,o2}
    __shared__ float red_c[WAVES], red_l[WAVES];

    const int nseg = blockIdx.x;
    const int b    = blockIdx.y;
    const int tid  = threadIdx.x;
    const int wv   = tid >> 6;
    const int lane = tid & 63;
    const int col  = lane & 31;          // MFMA col / A row index
    const int hi   = lane >> 5;          // k-group half

    // --- stage ori into LDS as bf16x4 (16 points per thread, coalesced-ish) ---
    #pragma unroll
    for (int i = 0; i < K/BLK; ++i) {
        int p = tid + i*BLK;
        const float* s = ori + (b*K + p)*3;
        float x = s[0], y = s[1], z = s[2];
        float o2 = x*x + y*y + z*z;
        ushort4 u;
        u.x = f2bf(-2.f*x); u.y = f2bf(-2.f*y);
        u.z = f2bf(-2.f*z); u.w = f2bf(o2);
        slds[p] = u;
    }

    // --- A fragment: this wave's 32 adv points, K=4 padded into K=16 ---
    // layout assumption: A lane l holds row (l&31), k = (l>>5)*8 + e
    const int n = nseg*NCHUNK + wv*32 + col;
    const float* ap = adv + (b*N + n)*3;
    float ax = ap[0], ay = ap[1], az = ap[2];
    float a2 = ax*ax + ay*ay + az*az;    // fp32, added after the min
    bf16x8 afrag;
    if (hi == 0) {
        afrag[0] = (short)f2bf(ax);
        afrag[1] = (short)f2bf(ay);
        afrag[2] = (short)f2bf(az);
        afrag[3] = (short)0x3F80;        // bf16 1.0
    } else {
        afrag[0] = 0; afrag[1] = 0; afrag[2] = 0; afrag[3] = 0;
    }
    afrag[4] = 0; afrag[5] = 0; afrag[6] = 0; afrag[7] = 0;

    __syncthreads();

    // --- main loop: 128 ori tiles of 32, two tiles per min3-merge ---
    f32x16 acc = {INFINITY,INFINITY,INFINITY,INFINITY,
                  INFINITY,INFINITY,INFINITY,INFINITY,
                  INFINITY,INFINITY,INFINITY,INFINITY,
                  INFINITY,INFINITY,INFINITY,INFINITY};
    const f32x16 zc = {0,0,0,0, 0,0,0,0, 0,0,0,0, 0,0,0,0};

    #pragma unroll 4
    for (int t = 0; t < K/32; t += 2) {
        ushort4 q0 = slds[t*32 + col];        // ds_read_b64, 2-way alias only
        ushort4 q1 = slds[(t+1)*32 + col];
        bf16x8 b0 = {(short)q0.x,(short)q0.y,(short)q0.z,(short)q0.w,0,0,0,0};
        bf16x8 b1 = {(short)q1.x,(short)q1.y,(short)q1.z,(short)q1.w,0,0,0,0};
        f32x16 c0 = __builtin_amdgcn_mfma_f32_32x32x16_bf16(afrag, b0, zc, 0,0,0);
        f32x16 c1 = __builtin_amdgcn_mfma_f32_32x32x16_bf16(afrag, b1, zc, 0,0,0);
        #pragma unroll
        for (int r = 0; r < 16; ++r)
            acc[r] = fminf(fminf(c0[r], c1[r]), acc[r]);   // v_min3_f32
    }

    // --- epilogue: min across cols (ori dim) within each 32-lane half ---
    #pragma unroll
    for (int r = 0; r < 16; ++r) {
        float v = acc[r];
        v = fminf(v, __shfl_xor(v, 1));
        v = fminf(v, __shfl_xor(v, 2));
        v = fminf(v, __shfl_xor(v, 4));
        v = fminf(v, __shfl_xor(v, 8));
        v = fminf(v, __shfl_xor(v, 16));
        acc[r] = v;                       // row-min, identical across the half
    }
    float rowsum = 0.f;
    #pragma unroll
    for (int r = 0; r < 16; ++r) rowsum += acc[r];
    rowsum += __shfl_xor(rowsum, 32);     // other half's 16 rows

    float a2s = a2;                       // sum a2 over the 32 points (per half)
    a2s += __shfl_xor(a2s, 1);
    a2s += __shfl_xor(a2s, 2);
    a2s += __shfl_xor(a2s, 4);
    a2s += __shfl_xor(a2s, 8);
    a2s += __shfl_xor(a2s, 16);

    if (lane == 0) red_c[wv] = rowsum + a2s;

    // --- obj L2 slice: 96 float4 per block ---
    float lv = 0.f;
    if (tid < OBJ_V4_PER_BLK) {
        int idx = b*OBJ_VEC4 + nseg*OBJ_V4_PER_BLK + tid;
        float4 a = reinterpret_cast<const float4*>(adv_obj)[idx];
        float4 o = reinterpret_cast<const float4*>(ori_obj)[idx];
        float dx = a.x - o.x, dy = a.y - o.y, dz = a.z - o.z, dw = a.w - o.w;
        lv = dx*dx + dy*dy + dz*dz + dw*dw;
    }
    #pragma unroll
    for (int off = 32; off; off >>= 1) lv += __shfl_down(lv, off);
    if (lane == 0) red_l[wv] = lv;

    __syncthreads();
    if (tid == 0) {
        csum[b*NSEG + nseg] = red_c[0] + red_c[1] + red_c[2] + red_c[3];
        lsq [b*NSEG + nseg] = red_l[0] + red_l[1] + red_l[2] + red_l[3];
    }
}

__global__ __launch_bounds__(256) void final_kernel(
    const float* __restrict__ csum, const float* __restrict__ lsq,
    const float* __restrict__ w, float* __restrict__ out)
{
    const int tid = threadIdx.x;           // 256 threads, 512 partials each arr
    float c = csum[2*tid] + csum[2*tid + 1];
    float l = lsq [2*tid] + lsq [2*tid + 1];
    // 16 partial-pairs per batch live in one 16-lane group
    #pragma unroll
    for (int off = 8; off; off >>= 1) {
        c += __shfl_down(c, off, 16);
        l += __shfl_down(l, off, 16);
    }
    __shared__ float sc[B], sl[B];
    int bb = tid >> 4;
    if ((tid & 15) == 0) { sc[bb] = c; sl[bb] = l; }
    __syncthreads();
    if (tid < 64) {
        float cc = 0.f, ll = 0.f;
        if (tid < B) {
            float wt = w[tid];
            cc = (sc[tid] / (float)N) * wt;
            ll = sqrtf(sl[tid] + EPS_F) * wt;
        }
        #pragma unroll
        for (int off = 8; off; off >>= 1) {
            cc += __shfl_down(cc, off);
            ll += __shfl_down(ll, off);
        }
        if (tid == 0) out[0] = ll / (float)B + CD_W * (cc / (float)B);
    }
}

extern "C" void kernel_launch(void* const* d_in, const int* in_sizes, int n_in,
                              void* d_out, int out_size, void* d_ws, size_t ws_size,
                              hipStream_t stream)
{
    const float* adv_pc  = (const float*)d_in[0];
    const float* ori_pc  = (const float*)d_in[1];
    const float* adv_obj = (const float*)d_in[2];
    const float* ori_obj = (const float*)d_in[3];
    const float* weights = (const float*)d_in[4];
    float* out = (float*)d_out;
    float* ws  = (float*)d_ws;

    float* csum = ws + CS_OFF;
    float* lsq  = ws + LS_OFF;

    // 1) fused MFMA chamfer + obj-L2 partials: grid = (NSEG, B) = 512 blocks
    chamfer_mfma_kernel<<<dim3(NSEG, B), dim3(BLK), 0, stream>>>(
        adv_pc, ori_pc, adv_obj, ori_obj, csum, lsq);

    // 2) weighted final combine (1 block)
    final_kernel<<<dim3(1), dim3(256), 0, stream>>>(csum, lsq, weights, out);
}